// Round 3
// baseline (246.658 us; speedup 1.0000x reference)
//
#include <hip/hip_runtime.h>
#include <math.h>

// out = gamma * (S * x) + x  ==  (1 + gamma*S) * x
// S = (p+1)/(pi*(N-1)^2) * sum_{i,j in [0,N)} cos(q * atan2(j, i)),  p=2, q=1, N=256
// S is data-independent -> computed on host once; gamma read on device (restored each call).
//
// v4: 8x unrolled grid-cyclic (8 independent global_load_dwordx4 in flight per
// thread) like v3, but sized from out_size at runtime with per-access bounds
// guards (v3 hard-coded coverage and core-dumped -> never assume dispatch size).

typedef float v4f __attribute__((ext_vector_type(4)));

#define UNROLL 8

__global__ __launch_bounds__(256) void zam_scale_kernel(
    const v4f* __restrict__ x,
    const float* __restrict__ gamma,
    v4f* __restrict__ out,
    float S, int n4, int nthreads)
{
    int tid = (int)(blockIdx.x * blockDim.x + threadIdx.x);
    float scale = fmaf(gamma[0], S, 1.0f);

    v4f v[UNROLL];
#pragma unroll
    for (int u = 0; u < UNROLL; ++u) {
        int i = tid + u * nthreads;
        if (i < n4) v[u] = x[i];        // independent loads issue back-to-back
    }
#pragma unroll
    for (int u = 0; u < UNROLL; ++u) {
        int i = tid + u * nthreads;
        if (i < n4) out[i] = v[u] * scale;
    }
}

static float compute_S() {
    const int N = 256;
    const double p = 2.0, q = 1.0;
    double s = 0.0;
    for (int i = 0; i < N; ++i) {
        for (int j = 0; j < N; ++j) {
            // atan2(0,0) == 0 in C, matching jnp.arctan2(0,0) == 0
            s += cos(q * atan2((double)j, (double)i));
        }
    }
    return (float)(s * (p + 1.0) / (M_PI * (double)(N - 1) * (double)(N - 1)));
}

extern "C" void kernel_launch(void* const* d_in, const int* in_sizes, int n_in,
                              void* d_out, int out_size, void* d_ws, size_t ws_size,
                              hipStream_t stream) {
    const float* x     = (const float*)d_in[0];
    const float* gamma = (const float*)d_in[1];
    float* out         = (float*)d_out;

    static const float S = compute_S();  // deterministic host constant

    int n  = out_size;                  // floats (8*64*256*256 = 33554432)
    int n4 = n / 4;                     // float4 count (divisible)
    int block = 256;
    int per_block = block * UNROLL;     // 2048 float4 per block
    int grid = (n4 + per_block - 1) / per_block;   // 4096 for the bench size
    int nthreads = grid * block;

    zam_scale_kernel<<<grid, block, 0, stream>>>(
        (const v4f*)x, gamma, (v4f*)out, S, n4, nthreads);
}

// Round 6
// 228.797 us; speedup vs baseline: 1.0781x; 1.0781x over previous
//
#include <hip/hip_runtime.h>
#include <math.h>

// out = gamma * (S * x) + x  ==  (1 + gamma*S) * x
// S = (p+1)/(pi*(N-1)^2) * sum_{i,j in [0,N)} cos(q * atan2(j, i)),  p=2, q=1, N=256
// S is data-independent -> computed on host once; gamma read on device (restored each call).
//
// v6 == v5 structure (two prior attempts died to container-level infra
// failures; kernel renamed + tail simplified to rule out artifact caching):
// block-contiguous 4x unroll. v4 post-mortem: grid-cyclic 16MB strides +
// per-access exec-mask guards -> 104 VGPR, 18% occupancy, 2 TB/s. Fix: 16KB
// contiguous tile per block (thread t handles t, t+256, t+512, t+768), one
// block-uniform bounds check for the fast path (no per-access guards, low
// VGPR), 4 independent dwordx4 loads in flight. Tail handled by a guarded
// scalar-float loop (covers both partial float4s and out_size % 4).

typedef float v4f __attribute__((ext_vector_type(4)));

#define UNROLL 4
#define BLOCK  256

__global__ __launch_bounds__(BLOCK) void zam_scale_v6(
    const v4f* __restrict__ x,
    const float* __restrict__ gamma,
    v4f* __restrict__ out,
    float S, int n4, int nfloat)
{
    int base = (int)blockIdx.x * (BLOCK * UNROLL);
    int t = (int)threadIdx.x;
    float scale = fmaf(gamma[0], S, 1.0f);

    if (base + BLOCK * UNROLL <= n4) {
        // fast path: whole 1024-float4 tile in bounds (block-uniform branch)
        v4f v[UNROLL];
#pragma unroll
        for (int u = 0; u < UNROLL; ++u)
            v[u] = x[base + t + u * BLOCK];      // 4 independent 16B loads
#pragma unroll
        for (int u = 0; u < UNROLL; ++u)
            out[base + t + u * BLOCK] = v[u] * scale;
    } else {
        // tail block: guarded scalar-float loop over this block's span
        const float* xf = (const float*)x;
        float* of = (float*)out;
        int fbase = base * 4;                    // first float of this tile
#pragma unroll
        for (int u = 0; u < UNROLL * 4; ++u) {
            int idx = fbase + t + u * BLOCK;
            if (idx < nfloat) of[idx] = xf[idx] * scale;
        }
    }
}

static float compute_S() {
    const int N = 256;
    const double p = 2.0, q = 1.0;
    double s = 0.0;
    for (int i = 0; i < N; ++i) {
        for (int j = 0; j < N; ++j) {
            // atan2(0,0) == 0 in C, matching jnp.arctan2(0,0) == 0
            s += cos(q * atan2((double)j, (double)i));
        }
    }
    return (float)(s * (p + 1.0) / (M_PI * (double)(N - 1) * (double)(N - 1)));
}

extern "C" void kernel_launch(void* const* d_in, const int* in_sizes, int n_in,
                              void* d_out, int out_size, void* d_ws, size_t ws_size,
                              hipStream_t stream) {
    const float* x     = (const float*)d_in[0];
    const float* gamma = (const float*)d_in[1];
    float* out         = (float*)d_out;

    static const float S = compute_S();  // deterministic host constant

    int nfloat = out_size;              // floats (8*64*256*256 = 33554432)
    int n4 = nfloat / 4;                // float4 count (8388608, divisible)
    int per_block = BLOCK * UNROLL;     // 1024 float4 per block
    int grid = (n4 + per_block - 1) / per_block;  // 8192 for the bench size
    if (grid * per_block < nfloat / 4 + 1) grid += 1;  // ensure tail floats covered
    if (grid < 1) grid = 1;             // tiny-dispatch safety

    zam_scale_v6<<<grid, BLOCK, 0, stream>>>(
        (const v4f*)x, gamma, (v4f*)out, S, n4, nfloat);
}